// Round 10
// baseline (37986.215 us; speedup 1.0000x reference)
//
#include <hip/hip_runtime.h>
#include <math.h>

// ---------------- helpers ----------------
__device__ __forceinline__ float block_reduce(float v, float* red) {
  int tid = threadIdx.x;
  red[tid] = v; __syncthreads();
  for (int s = 128; s >= 1; s >>= 1) {
    if (tid < s) red[tid] += red[tid + s];
    __syncthreads();
  }
  float r = red[0];
  __syncthreads();
  return r;
}

__global__ __launch_bounds__(256) void sentinel_kernel(float* __restrict__ out, int n, float v) {
  int i = blockIdx.x * 256 + threadIdx.x;
  if (i < n) out[i] = v;
}

// ---------------- BatchNorm stats ----------------
__global__ __launch_bounds__(256) void bn_stats_kernel(
    const float* __restrict__ tok, const float* __restrict__ g,
    const float* __restrict__ bb, float* __restrict__ ss) {
  __shared__ float red[256];
  const int d = blockIdx.x;
  float sum = 0.f, sumsq = 0.f;
  for (int s = threadIdx.x; s < 4096; s += 256) {
    float v = tok[s * 64 + d];
    sum += v; sumsq += v * v;
  }
  sum = block_reduce(sum, red);
  sumsq = block_reduce(sumsq, red);
  if (threadIdx.x == 0) {
    float mu = sum * (1.f / 4096.f);
    float var = sumsq * (1.f / 4096.f) - mu * mu;
    float sc = g[d] * rsqrtf(fmaxf(var, 0.f) + 1e-5f);
    ss[d] = sc;
    ss[64 + d] = bb[d] - mu * sc;
  }
}

__global__ __launch_bounds__(256) void tn_kernel(
    const float* __restrict__ tok, const float* __restrict__ ss,
    float* __restrict__ tn) {
  int idx = blockIdx.x * 256 + threadIdx.x;
  int d = idx & 63;
  tn[idx] = tok[idx] * ss[d] + ss[64 + d];
}

__global__ __launch_bounds__(256) void reverse_kernel(
    const float* __restrict__ x0, float* __restrict__ x0r) {
  int idx = blockIdx.x * 256 + threadIdx.x;
  int row = idx >> 9, e = idx & 511;
  int b = row >> 10, t = row & 1023;
  x0r[idx] = x0[((size_t)((b << 10) + (1023 - t))) * 512 + e];
}

// ---------------- row LayerNorm (N = 512 or 256) ----------------
__global__ __launch_bounds__(256) void ln_kernel(
    const float* __restrict__ x, const float* __restrict__ g,
    const float* __restrict__ b, float* __restrict__ out, int N) {
  __shared__ float red[256];
  const size_t r = blockIdx.x;
  const int tid = threadIdx.x;
  float v0 = x[r * N + tid];
  float v1 = (N > 256) ? x[r * N + 256 + tid] : 0.f;
  float sum = block_reduce(v0 + v1, red);
  float sumsq = block_reduce(v0 * v0 + v1 * v1, red);
  float mean = sum / (float)N;
  float var = sumsq / (float)N - mean * mean;
  float rs = rsqrtf(fmaxf(var, 0.f) + 1e-5f);
  out[r * N + tid] = (v0 - mean) * rs * g[tid] + b[tid];
  if (N > 256)
    out[r * N + 256 + tid] = (v1 - mean) * rs * g[256 + tid] + b[256 + tid];
}

// --------- GEMM (f32, tiled scalar): out[M,N] = A@W + bias (+resid)(act) ---------
template <int ACT>  // 0 none, 1 gelu(exact), 2 tanh
__global__ __launch_bounds__(256) void gemm3(
    const float* __restrict__ A, const float* __restrict__ W,
    const float* __restrict__ bias, const float* resid,
    float* out, int M, int N, int K) {
  __shared__ float As[16][65];   // As[k][m]
  __shared__ float Bs[16][65];   // Bs[k][n]
  const int tid = threadIdx.x;
  const int tx = tid & 15, ty = tid >> 4;
  const int n0 = blockIdx.x * 64, m0 = blockIdx.y * 64;
  float acc[4][4] = {};
  for (int k0 = 0; k0 < K; k0 += 16) {
    for (int idx = tid; idx < 1024; idx += 256) {
      int ka = idx & 15, ma = idx >> 4;
      As[ka][ma] = A[(size_t)(m0 + ma) * K + (k0 + ka)];
      int nb = idx & 63, kb = idx >> 6;
      Bs[kb][nb] = W[(size_t)(k0 + kb) * N + (n0 + nb)];
    }
    __syncthreads();
    for (int kq = 0; kq < 16; ++kq) {
      float a0 = As[kq][ty * 4 + 0], a1 = As[kq][ty * 4 + 1];
      float a2 = As[kq][ty * 4 + 2], a3 = As[kq][ty * 4 + 3];
      float b0 = Bs[kq][tx * 4 + 0], b1 = Bs[kq][tx * 4 + 1];
      float b2 = Bs[kq][tx * 4 + 2], b3 = Bs[kq][tx * 4 + 3];
      acc[0][0] += a0 * b0; acc[0][1] += a0 * b1; acc[0][2] += a0 * b2; acc[0][3] += a0 * b3;
      acc[1][0] += a1 * b0; acc[1][1] += a1 * b1; acc[1][2] += a1 * b2; acc[1][3] += a1 * b3;
      acc[2][0] += a2 * b0; acc[2][1] += a2 * b1; acc[2][2] += a2 * b2; acc[2][3] += a2 * b3;
      acc[3][0] += a3 * b0; acc[3][1] += a3 * b1; acc[3][2] += a3 * b2; acc[3][3] += a3 * b3;
    }
    __syncthreads();
  }
#pragma unroll
  for (int i = 0; i < 4; ++i) {
    int m = m0 + ty * 4 + i;
#pragma unroll
    for (int j = 0; j < 4; ++j) {
      int n = n0 + tx * 4 + j;
      float v = acc[i][j] + bias[n];
      if (resid) v += resid[(size_t)m * N + n];
      if (ACT == 1) v = 0.5f * v * (1.f + erff(v * 0.70710678118654752f));
      if (ACT == 2) v = tanhf(v);
      out[(size_t)m * N + n] = v;
    }
  }
}

// ---------------- attention: one 64-thread block per (b,h,tf) ----------------
__global__ __launch_bounds__(64) void attn_kernel(
    const float* __restrict__ q, const float* __restrict__ k,
    const float* __restrict__ v, const float* __restrict__ mask,
    float* __restrict__ y, int rev) {
  const int tf = blockIdx.x, h = blockIdx.y, b = blockIdx.z;
  const int smax = (tf + 1) * 8;
  const int tid = threadIdx.x;  // 0..63
  __shared__ float S[8][1024];
  __shared__ float qs[8][64];
  __shared__ float red[64];
  for (int i = tid; i < 512; i += 64) {
    int j = i >> 6, d = i & 63;
    qs[j][d] = q[((size_t)(b * 1024 + tf * 8 + j)) * 512 + h * 64 + d];
  }
  __syncthreads();
  for (int s = tid; s < smax; s += 64) {
    int sidx = rev ? (1023 - s) : s;
    bool ok = mask[b * 1024 + sidx] > 0.f;
    const float* krow = k + ((size_t)(b * 1024 + s)) * 512 + h * 64;
    for (int j = 0; j < 8; ++j) {
      float dot = 0.f;
      for (int d = 0; d < 64; ++d) dot += qs[j][d] * krow[d];
      S[j][s] = ok ? dot * 0.125f : -1e30f;
    }
  }
  __syncthreads();
  for (int j = 0; j < 8; ++j) {
    float lm = -1e30f;
    for (int s = tid; s < smax; s += 64) lm = fmaxf(lm, S[j][s]);
    red[tid] = lm; __syncthreads();
    for (int st = 32; st >= 1; st >>= 1) {
      if (tid < st) red[tid] = fmaxf(red[tid], red[tid + st]);
      __syncthreads();
    }
    float m = red[0]; __syncthreads();
    float ls = 0.f;
    for (int s = tid; s < smax; s += 64) {
      float sv = S[j][s];
      float e = (sv > -1e29f) ? __expf(sv - m) : 0.f;
      S[j][s] = e; ls += e;
    }
    red[tid] = ls; __syncthreads();
    for (int st = 32; st >= 1; st >>= 1) {
      if (tid < st) red[tid] += red[tid + st];
      __syncthreads();
    }
    float inv = 1.f / fmaxf(red[0], 1e-30f); __syncthreads();
    for (int s = tid; s < smax; s += 64) S[j][s] *= inv;
    __syncthreads();
  }
  {
    const int d = tid;
    float acc[8] = {0.f, 0.f, 0.f, 0.f, 0.f, 0.f, 0.f, 0.f};
    for (int s = 0; s < smax; ++s) {
      float vd = v[((size_t)(b * 1024 + s)) * 512 + h * 64 + d];
      for (int j = 0; j < 8; ++j) acc[j] += S[j][s] * vd;
    }
    for (int j = 0; j < 8; ++j)
      y[((size_t)(b * 1024 + tf * 8 + j)) * 512 + h * 64 + d] = acc[j];
  }
}

// ---------------- frame mean (+ FLOAT32 output write) ----------------
__global__ __launch_bounds__(256) void frame_mean_kernel(
    const float* __restrict__ xo, float* __restrict__ xf,
    float* __restrict__ outf) {
  int row = blockIdx.x;       // b*128+tf
  int o = threadIdx.x;
  float s = 0.f;
#pragma unroll
  for (int c = 0; c < 8; ++c) s += xo[((size_t)row * 8 + c) * 256 + o];
  s *= 0.125f;
  xf[row * 256 + o] = s;
  if (outf) outf[row * 256 + o] = s;   // output is FLOAT32 (reference returns f32)
}

// ---------------- losses ----------------
__global__ __launch_bounds__(256) void loss_reg_kernel(
    const float* __restrict__ pd, const float* __restrict__ tok,
    const float* __restrict__ mask, float* __restrict__ acc, int rev) {
  __shared__ float red[256];
  float local = 0.f;
  for (int idx = blockIdx.x * 256 + threadIdx.x; idx < 260096; idx += gridDim.x * 256) {
    int b = idx / 65024, r2 = idx % 65024;
    int t = r2 >> 6, d = r2 & 63;
    float pred = pd[((size_t)((b << 10) + t)) * 64 + d] * mask[(b << 10) + t];
    int tt = rev ? (1015 - t) : (t + 8);
    float tgt = tok[((size_t)((b << 10) + tt)) * 64 + d] * mask[(b << 10) + tt];
    float df = pred - tgt;
    local += df * df;
  }
  float s = block_reduce(local, red);
  if (threadIdx.x == 0) atomicAdd(acc, s);
}

// frame-level reversal preserves within-frame order: rev target t=(126-i)*8+c
__global__ __launch_bounds__(256) void loss_fr_kernel(
    const float* __restrict__ pf, const float* __restrict__ tok,
    const float* __restrict__ mask, float* __restrict__ acc, int rev) {
  __shared__ float red[256];
  float local = 0.f;
  for (int idx = blockIdx.x * 256 + threadIdx.x; idx < 260096; idx += gridDim.x * 256) {
    int b = idx / 65024, r2 = idx % 65024;
    int i = r2 >> 9, u = r2 & 511;
    float pred = pf[((size_t)(b * 128 + i)) * 512 + u];
    int c = u >> 6;
    int t = rev ? ((126 - i) * 8 + c) : ((i + 1) * 8 + c);
    float tgt = tok[((size_t)((b << 10) + t)) * 64 + (u & 63)] * mask[(b << 10) + t];
    float df = pred - tgt;
    local += df * df;
  }
  float s = block_reduce(local, red);
  if (threadIdx.x == 0) atomicAdd(acc, s);
}

__global__ void finalize_kernel(const float* __restrict__ acc, float* __restrict__ out) {
  int i = threadIdx.x;
  if (i < 4) out[131072 + i] = acc[i] * (1.0f / 260096.0f);
}

extern "C" void kernel_launch(void* const* d_in, const int* in_sizes, int n_in,
                              void* d_out, int out_size, void* d_ws, size_t ws_size,
                              hipStream_t stream) {
  float* ws = (float*)d_ws;
  const size_t OFF_SS   = 0;
  const size_t OFF_LACC = 128;
  const size_t OFF_TN   = 256;
  const size_t OFF_X0   = OFF_TN + 262144;
  const size_t OFF_X0R  = OFF_X0 + 2097152;
  const size_t OFF_X    = OFF_X0R + 2097152;
  const size_t OFF_H    = OFF_X + 2097152;
  const size_t OFF_QKVY = OFF_H + 2097152;
  const size_t OFF_XO   = OFF_QKVY + 8388608;
  const size_t OFF_HD   = OFF_XO + 1048576;
  const size_t OFF_HD2  = OFF_HD + 1048576;
  const size_t OFF_PD   = OFF_HD2 + 1048576;
  const size_t OFF_XF   = OFF_PD + 262144;
  const size_t OFF_HF   = OFF_XF + 131072;
  const size_t OFF_HF2  = OFF_HF + 131072;
  const size_t OFF_PF   = OFF_HF2 + 131072;
  const size_t TOTAL    = OFF_PF + 262144;

  float* ss   = ws + OFF_SS;
  float* lacc = ws + OFF_LACC;
  float* tn   = ws + OFF_TN;
  float* x0   = ws + OFF_X0;
  float* x0r  = ws + OFF_X0R;
  float* x    = ws + OFF_X;
  float* h    = ws + OFF_H;
  float* q    = ws + OFF_QKVY;
  float* kk   = ws + OFF_QKVY + 2097152;
  float* vv   = ws + OFF_QKVY + 4194304;
  float* yb   = ws + OFF_QKVY + 6291456;
  float* u    = ws + OFF_QKVY;  // alias (MLP phase only)
  float* xo   = ws + OFF_XO;
  float* hd   = ws + OFF_HD;
  float* hd2  = ws + OFF_HD2;
  float* pd   = ws + OFF_PD;
  float* xf   = ws + OFF_XF;
  float* hf   = ws + OFF_HF;
  float* hf2  = ws + OFF_HF2;
  float* pf   = ws + OFF_PF;
  float* out_f = (float*)d_out;   // OUTPUT IS FLOAT32

  static const int EXPECTED[39] = {
      262144, 4096, 4096, 64, 64, 32768, 512, 3072, 3072, 3072, 3072,
      1572864, 3072, 1572864, 3072, 1572864, 3072, 1572864, 3072,
      6291456, 12288, 6291456, 3072, 512, 512, 131072, 256, 65536, 256,
      256, 256, 16384, 64, 65536, 256, 256, 256, 131072, 512};
  bool manifest_ok = (n_in == 39) && (ws_size >= TOTAL * sizeof(float));
  if (manifest_ok)
    for (int i = 0; i < 39; ++i)
      if (in_sizes[i] != EXPECTED[i]) { manifest_ok = false; break; }
  if (!manifest_ok) {
    hipLaunchKernelGGL(sentinel_kernel, dim3((out_size + 255) / 256), dim3(256), 0, stream,
                       out_f, out_size, 2000.0f);
    return;
  }

  const float* tok    = (const float*)d_in[0];
  const float* mask   = (const float*)d_in[2];
  const float* bn_g   = (const float*)d_in[3];
  const float* bn_b   = (const float*)d_in[4];
  const float* We     = (const float*)d_in[5];
  const float* be     = (const float*)d_in[6];
  const float* ln1_g  = (const float*)d_in[7];
  const float* ln1_b  = (const float*)d_in[8];
  const float* ln2_g  = (const float*)d_in[9];
  const float* ln2_b  = (const float*)d_in[10];
  const float* Wq     = (const float*)d_in[11];
  const float* bq     = (const float*)d_in[12];
  const float* Wk     = (const float*)d_in[13];
  const float* bk     = (const float*)d_in[14];
  const float* Wv     = (const float*)d_in[15];
  const float* bv     = (const float*)d_in[16];
  const float* Wo     = (const float*)d_in[17];
  const float* bo     = (const float*)d_in[18];
  const float* W1     = (const float*)d_in[19];
  const float* b1     = (const float*)d_in[20];
  const float* W2     = (const float*)d_in[21];
  const float* b2     = (const float*)d_in[22];
  const float* lnf_g  = (const float*)d_in[23];
  const float* lnf_b  = (const float*)d_in[24];
  const float* Wp     = (const float*)d_in[25];
  const float* bp     = (const float*)d_in[26];
  const float* Wd1    = (const float*)d_in[27];
  const float* bd1    = (const float*)d_in[28];
  const float* lnd_g  = (const float*)d_in[29];
  const float* lnd_b  = (const float*)d_in[30];
  const float* Wd2    = (const float*)d_in[31];
  const float* bd2    = (const float*)d_in[32];
  const float* Wf1    = (const float*)d_in[33];
  const float* bf1    = (const float*)d_in[34];
  const float* lnfr_g = (const float*)d_in[35];
  const float* lnfr_b = (const float*)d_in[36];
  const float* Wf2    = (const float*)d_in[37];
  const float* bf2    = (const float*)d_in[38];

  auto G = [&](int act, const float* A, const float* W, const float* bias,
               const float* resid, float* out, int M, int N, int K) {
    dim3 g(N / 64, M / 64), b(256);
    if (act == 0) hipLaunchKernelGGL((gemm3<0>), g, b, 0, stream, A, W, bias, resid, out, M, N, K);
    else if (act == 1) hipLaunchKernelGGL((gemm3<1>), g, b, 0, stream, A, W, bias, resid, out, M, N, K);
    else hipLaunchKernelGGL((gemm3<2>), g, b, 0, stream, A, W, bias, resid, out, M, N, K);
  };

  hipMemsetAsync(lacc, 0, 4 * sizeof(float), stream);
  hipLaunchKernelGGL(bn_stats_kernel, dim3(64), dim3(256), 0, stream, tok, bn_g, bn_b, ss);
  hipLaunchKernelGGL(tn_kernel, dim3(1024), dim3(256), 0, stream, tok, ss, tn);
  G(0, tn, We, be, nullptr, x0, 4096, 512, 64);
  hipLaunchKernelGGL(reverse_kernel, dim3(8192), dim3(256), 0, stream, x0, x0r);

  for (int dir = 0; dir < 2; ++dir) {
    const float* xin = dir ? x0r : x0;
    for (int l = 0; l < 6; ++l) {
      const float* xl = (l == 0) ? xin : x;
      hipLaunchKernelGGL(ln_kernel, dim3(4096), dim3(256), 0, stream,
                         xl, ln1_g + l * 512, ln1_b + l * 512, h, 512);
      G(0, h, Wq + (size_t)l * 262144, bq + l * 512, nullptr, q, 4096, 512, 512);
      G(0, h, Wk + (size_t)l * 262144, bk + l * 512, nullptr, kk, 4096, 512, 512);
      G(0, h, Wv + (size_t)l * 262144, bv + l * 512, nullptr, vv, 4096, 512, 512);
      hipLaunchKernelGGL(attn_kernel, dim3(128, 8, 4), dim3(64), 0, stream,
                         q, kk, vv, mask, yb, dir);
      G(0, yb, Wo + (size_t)l * 262144, bo + l * 512, xl, x, 4096, 512, 512);
      hipLaunchKernelGGL(ln_kernel, dim3(4096), dim3(256), 0, stream,
                         x, ln2_g + l * 512, ln2_b + l * 512, h, 512);
      G(1, h, W1 + (size_t)l * 1048576, b1 + l * 2048, nullptr, u, 4096, 2048, 512);
      G(0, u, W2 + (size_t)l * 1048576, b2 + l * 512, x, x, 4096, 512, 2048);
    }
    hipLaunchKernelGGL(ln_kernel, dim3(4096), dim3(256), 0, stream, x, lnf_g, lnf_b, h, 512);
    G(0, h, Wp, bp, nullptr, xo, 4096, 256, 512);
    G(2, xo, Wd1, bd1, nullptr, hd, 4096, 256, 256);
    hipLaunchKernelGGL(ln_kernel, dim3(4096), dim3(256), 0, stream, hd, lnd_g, lnd_b, hd2, 256);
    G(0, hd2, Wd2, bd2, nullptr, pd, 4096, 64, 256);
    hipLaunchKernelGGL(loss_reg_kernel, dim3(256), dim3(256), 0, stream,
                       pd, tok, mask, lacc + (dir ? 1 : 0), dir);
    hipLaunchKernelGGL(frame_mean_kernel, dim3(512), dim3(256), 0, stream,
                       xo, xf, dir == 0 ? out_f : (float*)nullptr);
    G(2, xf, Wf1, bf1, nullptr, hf, 512, 256, 256);
    hipLaunchKernelGGL(ln_kernel, dim3(512), dim3(256), 0, stream, hf, lnfr_g, lnfr_b, hf2, 256);
    G(0, hf2, Wf2, bf2, nullptr, pf, 512, 512, 256);
    hipLaunchKernelGGL(loss_fr_kernel, dim3(256), dim3(256), 0, stream,
                       pf, tok, mask, lacc + (dir ? 3 : 2), dir);
  }
  hipLaunchKernelGGL(finalize_kernel, dim3(1), dim3(64), 0, stream, lacc, out_f);
}

// Round 11
// 12885.014 us; speedup vs baseline: 2.9481x; 2.9481x over previous
//
#include <hip/hip_runtime.h>
#include <math.h>

// ---------------- helpers ----------------
__device__ __forceinline__ float block_reduce(float v, float* red) {
  int tid = threadIdx.x;
  red[tid] = v; __syncthreads();
  for (int s = 128; s >= 1; s >>= 1) {
    if (tid < s) red[tid] += red[tid + s];
    __syncthreads();
  }
  float r = red[0];
  __syncthreads();
  return r;
}

__global__ __launch_bounds__(256) void sentinel_kernel(float* __restrict__ out, int n, float v) {
  int i = blockIdx.x * 256 + threadIdx.x;
  if (i < n) out[i] = v;
}

// ---------------- BatchNorm stats ----------------
__global__ __launch_bounds__(256) void bn_stats_kernel(
    const float* __restrict__ tok, const float* __restrict__ g,
    const float* __restrict__ bb, float* __restrict__ ss) {
  __shared__ float red[256];
  const int d = blockIdx.x;
  float sum = 0.f, sumsq = 0.f;
  for (int s = threadIdx.x; s < 4096; s += 256) {
    float v = tok[s * 64 + d];
    sum += v; sumsq += v * v;
  }
  sum = block_reduce(sum, red);
  sumsq = block_reduce(sumsq, red);
  if (threadIdx.x == 0) {
    float mu = sum * (1.f / 4096.f);
    float var = sumsq * (1.f / 4096.f) - mu * mu;
    float sc = g[d] * rsqrtf(fmaxf(var, 0.f) + 1e-5f);
    ss[d] = sc;
    ss[64 + d] = bb[d] - mu * sc;
  }
}

__global__ __launch_bounds__(256) void tn_kernel(
    const float* __restrict__ tok, const float* __restrict__ ss,
    float* __restrict__ tn) {
  int idx = blockIdx.x * 256 + threadIdx.x;
  int d = idx & 63;
  tn[idx] = tok[idx] * ss[d] + ss[64 + d];
}

__global__ __launch_bounds__(256) void reverse_kernel(
    const float* __restrict__ x0, float* __restrict__ x0r) {
  int idx = blockIdx.x * 256 + threadIdx.x;
  int row = idx >> 9, e = idx & 511;
  int b = row >> 10, t = row & 1023;
  x0r[idx] = x0[((size_t)((b << 10) + (1023 - t))) * 512 + e];
}

// ---------------- row LayerNorm (N = 512 or 256) ----------------
__global__ __launch_bounds__(256) void ln_kernel(
    const float* __restrict__ x, const float* __restrict__ g,
    const float* __restrict__ b, float* __restrict__ out, int N) {
  __shared__ float red[256];
  const size_t r = blockIdx.x;
  const int tid = threadIdx.x;
  float v0 = x[r * N + tid];
  float v1 = (N > 256) ? x[r * N + 256 + tid] : 0.f;
  float sum = block_reduce(v0 + v1, red);
  float sumsq = block_reduce(v0 * v0 + v1 * v1, red);
  float mean = sum / (float)N;
  float var = sumsq / (float)N - mean * mean;
  float rs = rsqrtf(fmaxf(var, 0.f) + 1e-5f);
  out[r * N + tid] = (v0 - mean) * rs * g[tid] + b[tid];
  if (N > 256)
    out[r * N + 256 + tid] = (v1 - mean) * rs * g[256 + tid] + b[256 + tid];
}

// --------- GEMM (f32, float4-vectorized): out[M,N] = A@W + bias (+resid)(act) ---------
#define BK 16
template <int ACT>  // 0 none, 1 gelu(exact), 2 tanh
__global__ __launch_bounds__(256) void gemm3(
    const float* __restrict__ A, const float* __restrict__ W,
    const float* __restrict__ bias, const float* resid,
    float* out, int M, int N, int K) {
  __shared__ float As[BK][64 + 4];
  __shared__ float Bs[BK][64 + 4];
  const int tid = threadIdx.x;
  const int tx = tid & 15, ty = tid >> 4;
  const int n0 = blockIdx.x * 64, m0 = blockIdx.y * 64;
  float acc[4][4] = {};
  for (int k0 = 0; k0 < K; k0 += BK) {
    {  // A tile: 64 rows x 16 k, 256 float4 loads
      int m = tid >> 2, kq = tid & 3;
      float4 a4 = *reinterpret_cast<const float4*>(A + (size_t)(m0 + m) * K + k0 + kq * 4);
      As[kq * 4 + 0][m] = a4.x; As[kq * 4 + 1][m] = a4.y;
      As[kq * 4 + 2][m] = a4.z; As[kq * 4 + 3][m] = a4.w;
    }
    {  // B tile: 16 k x 64 n, 256 float4 loads
      int kk = tid >> 4, nq = tid & 15;
      float4 b4 = *reinterpret_cast<const float4*>(W + (size_t)(k0 + kk) * N + n0 + nq * 4);
      Bs[kk][nq * 4 + 0] = b4.x; Bs[kk][nq * 4 + 1] = b4.y;
      Bs[kk][nq * 4 + 2] = b4.z; Bs[kk][nq * 4 + 3] = b4.w;
    }
    __syncthreads();
#pragma unroll
    for (int kq = 0; kq < BK; ++kq) {
      float4 av = *reinterpret_cast<const float4*>(&As[kq][ty * 4]);
      float4 bv = *reinterpret_cast<const float4*>(&Bs[kq][tx * 4]);
      acc[0][0] += av.x * bv.x; acc[0][1] += av.x * bv.y; acc[0][2] += av.x * bv.z; acc[0][3] += av.x * bv.w;
      acc[1][0] += av.y * bv.x; acc[1][1] += av.y * bv.y; acc[1][2] += av.y * bv.z; acc[1][3] += av.y * bv.w;
      acc[2][0] += av.z * bv.x; acc[2][1] += av.z * bv.y; acc[2][2] += av.z * bv.z; acc[2][3] += av.z * bv.w;
      acc[3][0] += av.w * bv.x; acc[3][1] += av.w * bv.y; acc[3][2] += av.w * bv.z; acc[3][3] += av.w * bv.w;
    }
    __syncthreads();
  }
#pragma unroll
  for (int i = 0; i < 4; ++i) {
    int m = m0 + ty * 4 + i;
#pragma unroll
    for (int j = 0; j < 4; ++j) {
      int n = n0 + tx * 4 + j;
      float v = acc[i][j] + bias[n];
      if (resid) v += resid[(size_t)m * N + n];
      if (ACT == 1) v = 0.5f * v * (1.f + erff(v * 0.70710678118654752f));
      if (ACT == 2) v = tanhf(v);
      out[(size_t)m * N + n] = v;
    }
  }
}

// ---------------- attention: one 256-thread block per (b, h, frame tf) ----------------
__global__ __launch_bounds__(256) void attn_kernel(
    const float* __restrict__ q, const float* __restrict__ k,
    const float* __restrict__ v, const float* __restrict__ mask,
    float* __restrict__ y, int rev) {
  const int tf = blockIdx.x, h = blockIdx.y, b = blockIdx.z;
  const int smax = (tf + 1) * 8;
  const int tid = threadIdx.x;
  __shared__ float S[8][1024];
  __shared__ float qs[8][64];
  __shared__ float red[256];
  for (int i = tid; i < 512; i += 256) {
    int j = i >> 6, d = i & 63;
    qs[j][d] = q[((size_t)(b * 1024 + tf * 8 + j)) * 512 + h * 64 + d] * 0.125f;
  }
  __syncthreads();
  // scores: keys distributed over 256 lanes, K-row in float4 registers
  for (int s = tid; s < smax; s += 256) {
    const float4* krow = reinterpret_cast<const float4*>(k + ((size_t)(b * 1024 + s)) * 512 + h * 64);
    float acc[8] = {0.f, 0.f, 0.f, 0.f, 0.f, 0.f, 0.f, 0.f};
#pragma unroll
    for (int i = 0; i < 16; ++i) {
      float4 kv = krow[i];
#pragma unroll
      for (int j = 0; j < 8; ++j)
        acc[j] += qs[j][i * 4 + 0] * kv.x + qs[j][i * 4 + 1] * kv.y +
                  qs[j][i * 4 + 2] * kv.z + qs[j][i * 4 + 3] * kv.w;
    }
    int sidx = rev ? (1023 - s) : s;
    bool ok = mask[b * 1024 + sidx] > 0.f;
#pragma unroll
    for (int j = 0; j < 8; ++j) S[j][s] = ok ? acc[j] : -1e30f;
  }
  __syncthreads();
  // softmax: 8 rows in parallel, 32 lanes per row
  {
    int j = tid >> 5, lane = tid & 31;
    float m = -1e30f;
    for (int s = lane; s < smax; s += 32) m = fmaxf(m, S[j][s]);
    for (int off = 16; off >= 1; off >>= 1) m = fmaxf(m, __shfl_xor(m, off, 32));
    float sum = 0.f;
    for (int s = lane; s < smax; s += 32) {
      float sv = S[j][s];
      float e = (sv > -1e29f) ? __expf(sv - m) : 0.f;
      S[j][s] = e; sum += e;
    }
    for (int off = 16; off >= 1; off >>= 1) sum += __shfl_xor(sum, off, 32);
    float inv = 1.f / fmaxf(sum, 1e-30f);
    for (int s = lane; s < smax; s += 32) S[j][s] *= inv;
  }
  __syncthreads();
  // PV: 4 chunks x 64 dims, LDS-tree combine
  const int d = tid & 63, chunk = tid >> 6;
  float acc[8] = {0.f, 0.f, 0.f, 0.f, 0.f, 0.f, 0.f, 0.f};
  for (int s = chunk; s < smax; s += 4) {
    float vd = v[((size_t)(b * 1024 + s)) * 512 + h * 64 + d];
#pragma unroll
    for (int j = 0; j < 8; ++j) acc[j] += S[j][s] * vd;
  }
#pragma unroll
  for (int j = 0; j < 8; ++j) {
    __syncthreads();
    red[tid] = acc[j];
    __syncthreads();
    if (tid < 64) {
      float r = red[tid] + red[tid + 64] + red[tid + 128] + red[tid + 192];
      y[((size_t)(b * 1024 + tf * 8 + j)) * 512 + h * 64 + tid] = r;
    }
  }
}

// ---------------- frame mean (+ FLOAT32 output write) ----------------
__global__ __launch_bounds__(256) void frame_mean_kernel(
    const float* __restrict__ xo, float* __restrict__ xf,
    float* __restrict__ outf) {
  int row = blockIdx.x;       // b*128+tf
  int o = threadIdx.x;
  float s = 0.f;
#pragma unroll
  for (int c = 0; c < 8; ++c) s += xo[((size_t)row * 8 + c) * 256 + o];
  s *= 0.125f;
  xf[row * 256 + o] = s;
  if (outf) outf[row * 256 + o] = s;
}

// ---------------- losses ----------------
__global__ __launch_bounds__(256) void loss_reg_kernel(
    const float* __restrict__ pd, const float* __restrict__ tok,
    const float* __restrict__ mask, float* __restrict__ acc, int rev) {
  __shared__ float red[256];
  float local = 0.f;
  for (int idx = blockIdx.x * 256 + threadIdx.x; idx < 260096; idx += gridDim.x * 256) {
    int b = idx / 65024, r2 = idx % 65024;
    int t = r2 >> 6, d = r2 & 63;
    float pred = pd[((size_t)((b << 10) + t)) * 64 + d] * mask[(b << 10) + t];
    int tt = rev ? (1015 - t) : (t + 8);
    float tgt = tok[((size_t)((b << 10) + tt)) * 64 + d] * mask[(b << 10) + tt];
    float df = pred - tgt;
    local += df * df;
  }
  float s = block_reduce(local, red);
  if (threadIdx.x == 0) atomicAdd(acc, s);
}

__global__ __launch_bounds__(256) void loss_fr_kernel(
    const float* __restrict__ pf, const float* __restrict__ tok,
    const float* __restrict__ mask, float* __restrict__ acc, int rev) {
  __shared__ float red[256];
  float local = 0.f;
  for (int idx = blockIdx.x * 256 + threadIdx.x; idx < 260096; idx += gridDim.x * 256) {
    int b = idx / 65024, r2 = idx % 65024;
    int i = r2 >> 9, u = r2 & 511;
    float pred = pf[((size_t)(b * 128 + i)) * 512 + u];
    int c = u >> 6;
    int t = rev ? ((126 - i) * 8 + c) : ((i + 1) * 8 + c);
    float tgt = tok[((size_t)((b << 10) + t)) * 64 + (u & 63)] * mask[(b << 10) + t];
    float df = pred - tgt;
    local += df * df;
  }
  float s = block_reduce(local, red);
  if (threadIdx.x == 0) atomicAdd(acc, s);
}

__global__ void finalize_kernel(const float* __restrict__ acc, float* __restrict__ out) {
  int i = threadIdx.x;
  if (i < 4) out[131072 + i] = acc[i] * (1.0f / 260096.0f);
}

extern "C" void kernel_launch(void* const* d_in, const int* in_sizes, int n_in,
                              void* d_out, int out_size, void* d_ws, size_t ws_size,
                              hipStream_t stream) {
  float* ws = (float*)d_ws;
  const size_t OFF_SS   = 0;
  const size_t OFF_LACC = 128;
  const size_t OFF_TN   = 256;
  const size_t OFF_X0   = OFF_TN + 262144;
  const size_t OFF_X0R  = OFF_X0 + 2097152;
  const size_t OFF_X    = OFF_X0R + 2097152;
  const size_t OFF_H    = OFF_X + 2097152;
  const size_t OFF_QKVY = OFF_H + 2097152;
  const size_t OFF_XO   = OFF_QKVY + 8388608;
  const size_t OFF_HD   = OFF_XO + 1048576;
  const size_t OFF_HD2  = OFF_HD + 1048576;
  const size_t OFF_PD   = OFF_HD2 + 1048576;
  const size_t OFF_XF   = OFF_PD + 262144;
  const size_t OFF_HF   = OFF_XF + 131072;
  const size_t OFF_HF2  = OFF_HF + 131072;
  const size_t OFF_PF   = OFF_HF2 + 131072;
  const size_t TOTAL    = OFF_PF + 262144;

  float* ss   = ws + OFF_SS;
  float* lacc = ws + OFF_LACC;
  float* tn   = ws + OFF_TN;
  float* x0   = ws + OFF_X0;
  float* x0r  = ws + OFF_X0R;
  float* x    = ws + OFF_X;
  float* h    = ws + OFF_H;
  float* q    = ws + OFF_QKVY;
  float* kk   = ws + OFF_QKVY + 2097152;
  float* vv   = ws + OFF_QKVY + 4194304;
  float* yb   = ws + OFF_QKVY + 6291456;
  float* u    = ws + OFF_QKVY;  // alias (MLP phase only)
  float* xo   = ws + OFF_XO;
  float* hd   = ws + OFF_HD;
  float* hd2  = ws + OFF_HD2;
  float* pd   = ws + OFF_PD;
  float* xf   = ws + OFF_XF;
  float* hf   = ws + OFF_HF;
  float* hf2  = ws + OFF_HF2;
  float* pf   = ws + OFF_PF;
  float* out_f = (float*)d_out;   // OUTPUT IS FLOAT32

  static const int EXPECTED[39] = {
      262144, 4096, 4096, 64, 64, 32768, 512, 3072, 3072, 3072, 3072,
      1572864, 3072, 1572864, 3072, 1572864, 3072, 1572864, 3072,
      6291456, 12288, 6291456, 3072, 512, 512, 131072, 256, 65536, 256,
      256, 256, 16384, 64, 65536, 256, 256, 256, 131072, 512};
  bool manifest_ok = (n_in == 39) && (ws_size >= TOTAL * sizeof(float));
  if (manifest_ok)
    for (int i = 0; i < 39; ++i)
      if (in_sizes[i] != EXPECTED[i]) { manifest_ok = false; break; }
  if (!manifest_ok) {
    hipLaunchKernelGGL(sentinel_kernel, dim3((out_size + 255) / 256), dim3(256), 0, stream,
                       out_f, out_size, 2000.0f);
    return;
  }

  const float* tok    = (const float*)d_in[0];
  const float* mask   = (const float*)d_in[2];
  const float* bn_g   = (const float*)d_in[3];
  const float* bn_b   = (const float*)d_in[4];
  const float* We     = (const float*)d_in[5];
  const float* be     = (const float*)d_in[6];
  const float* ln1_g  = (const float*)d_in[7];
  const float* ln1_b  = (const float*)d_in[8];
  const float* ln2_g  = (const float*)d_in[9];
  const float* ln2_b  = (const float*)d_in[10];
  const float* Wq     = (const float*)d_in[11];
  const float* bq     = (const float*)d_in[12];
  const float* Wk     = (const float*)d_in[13];
  const float* bk     = (const float*)d_in[14];
  const float* Wv     = (const float*)d_in[15];
  const float* bv     = (const float*)d_in[16];
  const float* Wo     = (const float*)d_in[17];
  const float* bo     = (const float*)d_in[18];
  const float* W1     = (const float*)d_in[19];
  const float* b1     = (const float*)d_in[20];
  const float* W2     = (const float*)d_in[21];
  const float* b2     = (const float*)d_in[22];
  const float* lnf_g  = (const float*)d_in[23];
  const float* lnf_b  = (const float*)d_in[24];
  const float* Wp     = (const float*)d_in[25];
  const float* bp     = (const float*)d_in[26];
  const float* Wd1    = (const float*)d_in[27];
  const float* bd1    = (const float*)d_in[28];
  const float* lnd_g  = (const float*)d_in[29];
  const float* lnd_b  = (const float*)d_in[30];
  const float* Wd2    = (const float*)d_in[31];
  const float* bd2    = (const float*)d_in[32];
  const float* Wf1    = (const float*)d_in[33];
  const float* bf1    = (const float*)d_in[34];
  const float* lnfr_g = (const float*)d_in[35];
  const float* lnfr_b = (const float*)d_in[36];
  const float* Wf2    = (const float*)d_in[37];
  const float* bf2    = (const float*)d_in[38];

  auto G = [&](int act, const float* A, const float* W, const float* bias,
               const float* resid, float* out, int M, int N, int K) {
    dim3 g(N / 64, M / 64), b(256);
    if (act == 0) hipLaunchKernelGGL((gemm3<0>), g, b, 0, stream, A, W, bias, resid, out, M, N, K);
    else if (act == 1) hipLaunchKernelGGL((gemm3<1>), g, b, 0, stream, A, W, bias, resid, out, M, N, K);
    else hipLaunchKernelGGL((gemm3<2>), g, b, 0, stream, A, W, bias, resid, out, M, N, K);
  };

  hipMemsetAsync(lacc, 0, 4 * sizeof(float), stream);
  hipLaunchKernelGGL(bn_stats_kernel, dim3(64), dim3(256), 0, stream, tok, bn_g, bn_b, ss);
  hipLaunchKernelGGL(tn_kernel, dim3(1024), dim3(256), 0, stream, tok, ss, tn);
  G(0, tn, We, be, nullptr, x0, 4096, 512, 64);
  hipLaunchKernelGGL(reverse_kernel, dim3(8192), dim3(256), 0, stream, x0, x0r);

  for (int dir = 0; dir < 2; ++dir) {
    const float* xin = dir ? x0r : x0;
    for (int l = 0; l < 6; ++l) {
      const float* xl = (l == 0) ? xin : x;
      hipLaunchKernelGGL(ln_kernel, dim3(4096), dim3(256), 0, stream,
                         xl, ln1_g + l * 512, ln1_b + l * 512, h, 512);
      G(0, h, Wq + (size_t)l * 262144, bq + l * 512, nullptr, q, 4096, 512, 512);
      G(0, h, Wk + (size_t)l * 262144, bk + l * 512, nullptr, kk, 4096, 512, 512);
      G(0, h, Wv + (size_t)l * 262144, bv + l * 512, nullptr, vv, 4096, 512, 512);
      hipLaunchKernelGGL(attn_kernel, dim3(128, 8, 4), dim3(256), 0, stream,
                         q, kk, vv, mask, yb, dir);
      G(0, yb, Wo + (size_t)l * 262144, bo + l * 512, xl, x, 4096, 512, 512);
      hipLaunchKernelGGL(ln_kernel, dim3(4096), dim3(256), 0, stream,
                         x, ln2_g + l * 512, ln2_b + l * 512, h, 512);
      G(1, h, W1 + (size_t)l * 1048576, b1 + l * 2048, nullptr, u, 4096, 2048, 512);
      G(0, u, W2 + (size_t)l * 1048576, b2 + l * 512, x, x, 4096, 512, 2048);
    }
    hipLaunchKernelGGL(ln_kernel, dim3(4096), dim3(256), 0, stream, x, lnf_g, lnf_b, h, 512);
    G(0, h, Wp, bp, nullptr, xo, 4096, 256, 512);
    G(2, xo, Wd1, bd1, nullptr, hd, 4096, 256, 256);
    hipLaunchKernelGGL(ln_kernel, dim3(4096), dim3(256), 0, stream, hd, lnd_g, lnd_b, hd2, 256);
    G(0, hd2, Wd2, bd2, nullptr, pd, 4096, 64, 256);
    hipLaunchKernelGGL(loss_reg_kernel, dim3(256), dim3(256), 0, stream,
                       pd, tok, mask, lacc + (dir ? 1 : 0), dir);
    hipLaunchKernelGGL(frame_mean_kernel, dim3(512), dim3(256), 0, stream,
                       xo, xf, dir == 0 ? out_f : (float*)nullptr);
    G(2, xf, Wf1, bf1, nullptr, hf, 512, 256, 256);
    hipLaunchKernelGGL(ln_kernel, dim3(512), dim3(256), 0, stream, hf, lnfr_g, lnfr_b, hf2, 256);
    G(0, hf2, Wf2, bf2, nullptr, pf, 512, 512, 256);
    hipLaunchKernelGGL(loss_fr_kernel, dim3(256), dim3(256), 0, stream,
                       pf, tok, mask, lacc + (dir ? 3 : 2), dir);
  }
  hipLaunchKernelGGL(finalize_kernel, dim3(1), dim3(64), 0, stream, lacc, out_f);
}